// Round 2
// baseline (22606.607 us; speedup 1.0000x reference)
//
#include <hip/hip_runtime.h>

// Problem constants (from reference)
#define PP 712740      // M*K points
#define MM 35637       // M
#define KK 20          // K neighbors
#define NF 15872       // N points in x_feat
// FEAT = 128 channels, W0 = 1.0, EPS = 1e-5

typedef _Float16 h16;

// ---------------------------------------------------------------------------
// Zero the stats accumulators (8 layers x 256 doubles) without hipMemsetAsync.
// ---------------------------------------------------------------------------
__global__ __launch_bounds__(256) void k_zero(double* __restrict__ gs) {
  const int t = threadIdx.x;
#pragma unroll
  for (int i = 0; i < 8; ++i) gs[i * 256 + t] = 0.0;
}

// ---------------------------------------------------------------------------
// Layer 0: z0[o][p] = sum_c conv0_w[o][c] * up[c][p]   (c=0..6, o=0..127)
// z stored fp16. Per-channel sum/sumsq of z0 accumulated into gs (fp64).
// ---------------------------------------------------------------------------
__global__ __launch_bounds__(256) void k_layer0(
    const float* __restrict__ up,    // [7][PP]
    const float* __restrict__ w0,    // [128][7]
    h16* __restrict__ z,             // [128][PP]
    double* __restrict__ gs)         // [256]: sum[128], sumsq[128]
{
  __shared__ double bred[4][256];
  const int t = threadIdx.x;
  const int lane = t & 63;
  double lS0 = 0, lS1 = 0, lQ0 = 0, lQ1 = 0;

  for (int p0 = blockIdx.x * 256; p0 < PP; p0 += gridDim.x * 256) {
    const int p = p0 + t;
    const bool act = p < PP;
    float u[7];
#pragma unroll
    for (int c = 0; c < 7; ++c) u[c] = act ? up[c * PP + p] : 0.f;

#pragma unroll 1
    for (int och = 0; och < 16; ++och) {
      float acc[8];
#pragma unroll
      for (int j = 0; j < 8; ++j) acc[j] = 0.f;
#pragma unroll
      for (int c = 0; c < 7; ++c) {
        const float uv = u[c];
#pragma unroll
        for (int j = 0; j < 8; ++j)
          acc[j] = fmaf(w0[(och * 8 + j) * 7 + c], uv, acc[j]);
      }
#pragma unroll
      for (int j = 0; j < 8; ++j) {
        const int o = och * 8 + j;
        float s = acc[j];
        float q = acc[j] * acc[j];
#pragma unroll
        for (int d = 32; d > 0; d >>= 1) {
          s += __shfl_xor(s, d, 64);
          q += __shfl_xor(q, d, 64);
        }
        if ((o & 63) == lane) {
          if (o < 64) { lS0 += (double)s; lQ0 += (double)q; }
          else        { lS1 += (double)s; lQ1 += (double)q; }
        }
        if (act) z[(size_t)o * PP + p] = (h16)acc[j];
      }
    }
  }
  const int w = t >> 6;
  bred[w][lane]       = lS0;
  bred[w][64 + lane]  = lS1;
  bred[w][128 + lane] = lQ0;
  bred[w][192 + lane] = lQ1;
  __syncthreads();
  double v = bred[0][t] + bred[1][t] + bred[2][t] + bred[3][t];
  atomicAdd(&gs[t], v);
}

// ---------------------------------------------------------------------------
// Middle layer (x7): a[c] = sin(fma(z[c][p], sc[c], sh[c])); z[o][p] = W a.
// In-place on fp16 z (each thread owns column p). Stats of new z into gso.
// ---------------------------------------------------------------------------
__global__ __launch_bounds__(256) void k_layer(
    h16* __restrict__ z,              // [128][PP], in-place
    const double* __restrict__ gsp,   // stats of previous layer output
    double* __restrict__ gso,         // stats of this layer output
    const float* __restrict__ W,      // [128][128]
    const float* __restrict__ gamma,  // [128]
    const float* __restrict__ beta)   // [128]
{
  __shared__ float sc_s[128], sh_s[128];
  __shared__ double bred[4][256];
  const int t = threadIdx.x;
  const int lane = t & 63;

  if (t < 128) {
    const double n = (double)PP;
    const double mu = gsp[t] / n;
    const double var = gsp[128 + t] / n - mu * mu;
    const float rstd = (float)(1.0 / sqrt(var + 1e-5));
    const float sc = rstd * gamma[t];
    sc_s[t] = sc;
    sh_s[t] = beta[t] - (float)mu * sc;
  }
  __syncthreads();

  double lS0 = 0, lS1 = 0, lQ0 = 0, lQ1 = 0;

  for (int p0 = blockIdx.x * 256; p0 < PP; p0 += gridDim.x * 256) {
    const int p = p0 + t;
    const bool act = p < PP;
    float a[128];
#pragma unroll
    for (int c = 0; c < 128; ++c) {
      const float zv = act ? (float)z[(size_t)c * PP + p] : 0.f;
      const float h = fmaf(zv, sc_s[c], sh_s[c]);
      a[c] = act ? __sinf(h) : 0.f;
    }

#pragma unroll 1
    for (int och = 0; och < 16; ++och) {
      float acc[8];
#pragma unroll
      for (int j = 0; j < 8; ++j) acc[j] = 0.f;
#pragma unroll
      for (int c = 0; c < 128; ++c) {
        const float av = a[c];
#pragma unroll
        for (int j = 0; j < 8; ++j)
          acc[j] = fmaf(W[(och * 8 + j) * 128 + c], av, acc[j]);
      }
#pragma unroll
      for (int j = 0; j < 8; ++j) {
        const int o = och * 8 + j;
        float s = acc[j];
        float q = acc[j] * acc[j];
#pragma unroll
        for (int d = 32; d > 0; d >>= 1) {
          s += __shfl_xor(s, d, 64);
          q += __shfl_xor(q, d, 64);
        }
        if ((o & 63) == lane) {
          if (o < 64) { lS0 += (double)s; lQ0 += (double)q; }
          else        { lS1 += (double)s; lQ1 += (double)q; }
        }
        if (act) z[(size_t)o * PP + p] = (h16)acc[j];
      }
    }
  }
  const int w = t >> 6;
  bred[w][lane]       = lS0;
  bred[w][64 + lane]  = lS1;
  bred[w][128 + lane] = lQ0;
  bred[w][192 + lane] = lQ1;
  __syncthreads();
  double v = bred[0][t] + bred[1][t] + bred[2][t] + bred[3][t];
  atomicAdd(&gso[t], v);
}

// ---------------------------------------------------------------------------
// Final conv (128->1) with BN7+sine: logit[p] = fb + sum_c fw[c]*sin(bn7(z)).
// ---------------------------------------------------------------------------
__global__ __launch_bounds__(256) void k_logits(
    const h16* __restrict__ z,
    const double* __restrict__ gsp,
    const float* __restrict__ gamma,
    const float* __restrict__ beta,
    const float* __restrict__ fw,
    const float* __restrict__ fb,
    float* __restrict__ logits)
{
  __shared__ float sc_s[128], sh_s[128];
  const int t = threadIdx.x;
  if (t < 128) {
    const double n = (double)PP;
    const double mu = gsp[t] / n;
    const double var = gsp[128 + t] / n - mu * mu;
    const float rstd = (float)(1.0 / sqrt(var + 1e-5));
    const float sc = rstd * gamma[t];
    sc_s[t] = sc;
    sh_s[t] = beta[t] - (float)mu * sc;
  }
  __syncthreads();

  for (int p0 = blockIdx.x * 256; p0 < PP; p0 += gridDim.x * 256) {
    const int p = p0 + t;
    if (p >= PP) continue;
    float acc = fb[0];
#pragma unroll
    for (int c = 0; c < 128; ++c) {
      const float h = fmaf((float)z[(size_t)c * PP + p], sc_s[c], sh_s[c]);
      acc = fmaf(fw[c], __sinf(h), acc);
    }
    logits[p] = acc;
  }
}

// ---------------------------------------------------------------------------
// Softmax over K=20 per m + gather-weighted sum of x_feat rows. 1 wave per m.
// ---------------------------------------------------------------------------
__global__ __launch_bounds__(256) void k_out(
    const float* __restrict__ logits,  // [PP]
    const int* __restrict__ idx,       // [MM][KK]
    const float* __restrict__ xf,      // [NF][128]
    float* __restrict__ out)           // [MM][128]
{
  const int gw = (int)((blockIdx.x * 256 + threadIdx.x) >> 6);
  const int lane = threadIdx.x & 63;
  if (gw >= MM) return;
  const int m = gw;

  float l[KK];
#pragma unroll
  for (int k = 0; k < KK; ++k) l[k] = logits[m * KK + k];
  float mx = l[0];
#pragma unroll
  for (int k = 1; k < KK; ++k) mx = fmaxf(mx, l[k]);
  float ssum = 0.f;
#pragma unroll
  for (int k = 0; k < KK; ++k) { l[k] = __expf(l[k] - mx); ssum += l[k]; }
  const float inv = 1.f / ssum;

  float a0 = 0.f, a1 = 0.f;
#pragma unroll
  for (int k = 0; k < KK; ++k) {
    const int r = idx[m * KK + k];
    const float wk = l[k] * inv;
    a0 = fmaf(wk, xf[r * 128 + lane], a0);
    a1 = fmaf(wk, xf[r * 128 + 64 + lane], a1);
  }
  out[m * 128 + lane] = a0;
  out[m * 128 + 64 + lane] = a1;
}

// ---------------------------------------------------------------------------
// Fallback (small workspace): recompute chain in registers per point.
// mode 0: accumulate stats of z_{jl} (output of conv #jl) into gso.
// mode 1: full chain (jl must be 7) -> logits.
// ---------------------------------------------------------------------------
__global__ __launch_bounds__(256) void k_chain(
    const float* __restrict__ up,     // [7][PP]
    const float* __restrict__ w0,     // [128][7]
    const float* __restrict__ wc,     // [7][128][128]
    const float* __restrict__ gam,    // [8][128]
    const float* __restrict__ bet,    // [8][128]
    const double* __restrict__ gs,    // [8][256] stats (filled progressively)
    double* __restrict__ gso,         // stats out (mode 0)
    int jl, int mode,
    const float* __restrict__ fw,
    const float* __restrict__ fb,
    float* __restrict__ logits)
{
  __shared__ float sc_s[8][128], sh_s[8][128];
  __shared__ double bred[4][256];
  const int t = threadIdx.x;
  const int lane = t & 63;

  const int nbn = (mode == 0) ? jl : 8;
  for (int i = t; i < nbn * 128; i += 256) {
    const int L = i >> 7, c = i & 127;
    const double n = (double)PP;
    const double mu = gs[L * 256 + c] / n;
    const double var = gs[L * 256 + 128 + c] / n - mu * mu;
    const float rstd = (float)(1.0 / sqrt(var + 1e-5));
    const float sc = rstd * gam[L * 128 + c];
    sc_s[L][c] = sc;
    sh_s[L][c] = bet[L * 128 + c] - (float)mu * sc;
  }
  __syncthreads();

  double lS0 = 0, lS1 = 0, lQ0 = 0, lQ1 = 0;

  for (int p0 = blockIdx.x * 256; p0 < PP; p0 += gridDim.x * 256) {
    const int p = p0 + t;
    const bool act = p < PP;

    float a[128];
    {
      float u[7];
#pragma unroll
      for (int c = 0; c < 7; ++c) u[c] = act ? up[c * PP + p] : 0.f;
#pragma unroll 1
      for (int och = 0; och < 16; ++och) {
#pragma unroll
        for (int j = 0; j < 8; ++j) {
          float acc = 0.f;
#pragma unroll
          for (int c = 0; c < 7; ++c)
            acc = fmaf(w0[(och * 8 + j) * 7 + c], u[c], acc);
          a[och * 8 + j] = acc;
        }
      }
    }

#pragma unroll 1
    for (int L = 0; L < jl; ++L) {
#pragma unroll
      for (int c = 0; c < 128; ++c)
        a[c] = act ? __sinf(fmaf(a[c], sc_s[L][c], sh_s[L][c])) : 0.f;
      float b[128];
      const float* W = wc + (size_t)L * 128 * 128;
#pragma unroll 1
      for (int och = 0; och < 16; ++och) {
#pragma unroll
        for (int j = 0; j < 8; ++j) {
          float acc = 0.f;
#pragma unroll
          for (int c = 0; c < 128; ++c)
            acc = fmaf(W[(och * 8 + j) * 128 + c], a[c], acc);
          b[och * 8 + j] = acc;
        }
      }
#pragma unroll
      for (int c = 0; c < 128; ++c) a[c] = b[c];
    }

    if (mode == 0) {
#pragma unroll
      for (int o = 0; o < 128; ++o) {
        float s = a[o];
        float q = a[o] * a[o];
#pragma unroll
        for (int d = 32; d > 0; d >>= 1) {
          s += __shfl_xor(s, d, 64);
          q += __shfl_xor(q, d, 64);
        }
        if ((o & 63) == lane) {
          if (o < 64) { lS0 += (double)s; lQ0 += (double)q; }
          else        { lS1 += (double)s; lQ1 += (double)q; }
        }
      }
    } else if (act) {
      float acc = fb[0];
#pragma unroll
      for (int c = 0; c < 128; ++c) {
        const float h = fmaf(a[c], sc_s[7][c], sh_s[7][c]);
        acc = fmaf(fw[c], __sinf(h), acc);
      }
      logits[p] = acc;
    }
  }

  if (mode == 0) {
    const int w = t >> 6;
    bred[w][lane]       = lS0;
    bred[w][64 + lane]  = lS1;
    bred[w][128 + lane] = lQ0;
    bred[w][192 + lane] = lQ1;
    __syncthreads();
    double v = bred[0][t] + bred[1][t] + bred[2][t] + bred[3][t];
    atomicAdd(&gso[t], v);
  }
}

// ---------------------------------------------------------------------------
extern "C" void kernel_launch(void* const* d_in, const int* in_sizes, int n_in,
                              void* d_out, int out_size, void* d_ws, size_t ws_size,
                              hipStream_t stream) {
  const float* xf  = (const float*)d_in[0];  // (1, N, 128)
  const float* up  = (const float*)d_in[1];  // (1, 7, M, K)  == [7][PP]
  const int*   idx = (const int*)d_in[2];    // (1, M, K)
  const float* w0  = (const float*)d_in[3];  // (128, 7)
  const float* wc  = (const float*)d_in[4];  // (7, 128, 128)
  const float* gam = (const float*)d_in[5];  // (8, 128)
  const float* bet = (const float*)d_in[6];  // (8, 128)
  const float* fw  = (const float*)d_in[7];  // (1, 128)
  const float* fb  = (const float*)d_in[8];  // (1,)
  float* out = (float*)d_out;

  char* ws = (char*)d_ws;
  const size_t zb     = (size_t)128 * PP * sizeof(h16);   // 182,461,440 B
  const size_t statsb = 8 * 256 * sizeof(double);         // 16,384 B
  const size_t logb   = (size_t)PP * sizeof(float);       // 2,850,960 B
  const int NB = 1024;
  const int nbo = (MM + 3) / 4;

  if (ws_size >= zb + statsb + logb) {
    // Fast path: fp16 activation buffer fits (≈176.7 MiB needed).
    h16* z = (h16*)ws;
    double* gs = (double*)(ws + zb);
    float* logits = (float*)(ws + zb + statsb);

    k_zero<<<1, 256, 0, stream>>>(gs);
    k_layer0<<<NB, 256, 0, stream>>>(up, w0, z, gs);
    for (int i = 1; i <= 7; ++i) {
      k_layer<<<NB, 256, 0, stream>>>(z,
                                      gs + (size_t)(i - 1) * 256,
                                      gs + (size_t)i * 256,
                                      wc + (size_t)(i - 1) * 128 * 128,
                                      gam + (size_t)(i - 1) * 128,
                                      bet + (size_t)(i - 1) * 128);
    }
    k_logits<<<NB, 256, 0, stream>>>(z, gs + 7 * 256, gam + 7 * 128,
                                     bet + 7 * 128, fw, fb, logits);
    k_out<<<nbo, 256, 0, stream>>>(logits, idx, xf, out);
  } else {
    // Fallback: recompute chain, needs only ≈2.9 MiB of workspace.
    double* gs = (double*)ws;
    float* logits = (float*)(ws + statsb);

    k_zero<<<1, 256, 0, stream>>>(gs);
    for (int j = 0; j <= 7; ++j) {
      k_chain<<<NB, 256, 0, stream>>>(up, w0, wc, gam, bet, gs,
                                      gs + (size_t)j * 256, j, 0,
                                      fw, fb, logits);
    }
    k_chain<<<NB, 256, 0, stream>>>(up, w0, wc, gam, bet, gs,
                                    nullptr, 7, 1, fw, fb, logits);
    k_out<<<nbo, 256, 0, stream>>>(logits, idx, xf, out);
  }
}

// Round 3
// 923.368 us; speedup vs baseline: 24.4828x; 24.4828x over previous
//
#include <hip/hip_runtime.h>

// Problem constants (from reference)
#define PP 712740      // M*K points
#define MM 35637       // M
#define KK 20          // K neighbors
#define NF 15872       // N points in x_feat
#define NTILES 44547   // ceil(PP/16) point-tiles of 16
// FEAT = 128 channels, W0 = 1.0, EPS = 1e-5

typedef _Float16 h16;
typedef __attribute__((ext_vector_type(8))) _Float16 f16x8;
typedef __attribute__((ext_vector_type(4))) float f32x4;

// ---------------------------------------------------------------------------
// Zero the stats accumulators (8 layers x 256 doubles).
// ---------------------------------------------------------------------------
__global__ __launch_bounds__(256) void k_zero(double* __restrict__ gs) {
  const int t = threadIdx.x;
#pragma unroll
  for (int i = 0; i < 8; ++i) gs[i * 256 + t] = 0.0;
}

// ---------------------------------------------------------------------------
// Layer 0 (K=7, VALU): z0[p][c] = sum_c7 w0[c][c7] * up[c7][p], z point-major
// f16 [PP][128]. Lane (q,ln) owns point p=tile*16+ln, channels ks*32+q*8+j.
// Stores are f16x8 chunks -> 64B-coalesced segments. Stats via per-lane fp32
// partials + end-of-kernel butterfly + LDS block reduce + fp64 atomics.
// ---------------------------------------------------------------------------
__global__ __launch_bounds__(256) void k_layer0(
    const float* __restrict__ up,    // [7][PP]
    const float* __restrict__ w0,    // [128][7]
    h16* __restrict__ z,             // [PP][128]
    double* __restrict__ gs)         // [256]: sum[128], sumsq[128]
{
  __shared__ float w0s[128 * 7];
  __shared__ double red[4][256];
  const int t = threadIdx.x;
  for (int i = t; i < 128 * 7; i += 256) w0s[i] = w0[i];
  __syncthreads();

  const int w = t >> 6;
  const int lane = t & 63;
  const int ln = lane & 15;
  const int q = lane >> 4;

  float sp[32], qp[32];
#pragma unroll
  for (int i = 0; i < 32; ++i) { sp[i] = 0.f; qp[i] = 0.f; }

  const int gw = blockIdx.x * 4 + w;
  for (int tile = gw; tile < NTILES; tile += gridDim.x * 4) {
    const int p = tile * 16 + ln;
    const bool act = p < PP;
    float u[7];
#pragma unroll
    for (int c7 = 0; c7 < 7; ++c7) u[c7] = act ? up[c7 * PP + p] : 0.f;

#pragma unroll
    for (int ks = 0; ks < 4; ++ks) {
      f16x8 o;
#pragma unroll
      for (int j = 0; j < 8; ++j) {
        const int c = ks * 32 + q * 8 + j;
        float acc = 0.f;
#pragma unroll
        for (int c7 = 0; c7 < 7; ++c7) acc = fmaf(w0s[c * 7 + c7], u[c7], acc);
        o[j] = (h16)acc;
        const int si = ks * 8 + j;
        sp[si] += acc;
        qp[si] = fmaf(acc, acc, qp[si]);
      }
      if (act) *(f16x8*)(z + (size_t)p * 128 + ks * 32 + q * 8) = o;
    }
  }

  // reduce across ln (16-lane groups): lanes with ln==0 hold channel sums
#pragma unroll
  for (int i = 0; i < 32; ++i) {
#pragma unroll
    for (int d = 1; d < 16; d <<= 1) {
      sp[i] += __shfl_xor(sp[i], d, 64);
      qp[i] += __shfl_xor(qp[i], d, 64);
    }
  }
  if (ln == 0) {
#pragma unroll
    for (int ks = 0; ks < 4; ++ks)
#pragma unroll
      for (int j = 0; j < 8; ++j) {
        const int c = ks * 32 + q * 8 + j;
        red[w][c] = (double)sp[ks * 8 + j];
        red[w][128 + c] = (double)qp[ks * 8 + j];
      }
  }
  __syncthreads();
  double v = red[0][t] + red[1][t] + red[2][t] + red[3][t];
  atomicAdd(&gs[t], v);
}

// ---------------------------------------------------------------------------
// Middle layer (x7), MFMA: per wave, tile = 16 points x 128 channels.
//   A (16x32 per kstep) = sin(bn(z_old)) fragments, built in-registers.
//   B = W rows as f16 fragments, persistent in VGPRs (8 ntiles x 4 ksteps).
//   D (point x channel) -> LDS transpose -> coalesced f16x8 global stores.
// Stats: per-lane running column sums from acc regs; butterfly at kernel end.
// ---------------------------------------------------------------------------
__global__ __launch_bounds__(256, 2) void k_layer(
    h16* __restrict__ z,              // [PP][128], in-place
    const double* __restrict__ gsp,   // stats of previous layer output
    double* __restrict__ gso,         // stats of this layer output
    const float* __restrict__ W,      // [128][128] fp32
    const float* __restrict__ gamma,  // [128]
    const float* __restrict__ beta)   // [128]
{
  __shared__ float sc_s[128], sh_s[128];
  __shared__ h16 tbuf[4][16 * 136];   // per-wave transpose tile (272B rows)
  __shared__ double red[4][256];
  const int t = threadIdx.x;
  if (t < 128) {
    const double n = (double)PP;
    const double mu = gsp[t] / n;
    const double var = gsp[128 + t] / n - mu * mu;
    const float rstd = (float)(1.0 / sqrt(var + 1e-5));
    const float sc = rstd * gamma[t];
    sc_s[t] = sc;
    sh_s[t] = beta[t] - (float)mu * sc;
  }
  __syncthreads();

  const int w = t >> 6;
  const int lane = t & 63;
  const int ln = lane & 15;
  const int q = lane >> 4;

  // Persistent B fragments: W[o=nt*16+ln][c=ks*32+q*8+j] -> f16
  f16x8 bfr[8][4];
#pragma unroll
  for (int nt = 0; nt < 8; ++nt) {
    const float* wrow = W + (size_t)(nt * 16 + ln) * 128;
#pragma unroll
    for (int ks = 0; ks < 4; ++ks) {
      const float* src = wrow + ks * 32 + q * 8;
      const float4 aa = *(const float4*)src;
      const float4 bb = *(const float4*)(src + 4);
      f16x8 b;
      b[0] = (h16)aa.x; b[1] = (h16)aa.y; b[2] = (h16)aa.z; b[3] = (h16)aa.w;
      b[4] = (h16)bb.x; b[5] = (h16)bb.y; b[6] = (h16)bb.z; b[7] = (h16)bb.w;
      bfr[nt][ks] = b;
    }
  }

  float sp[8], qp[8];
#pragma unroll
  for (int i = 0; i < 8; ++i) { sp[i] = 0.f; qp[i] = 0.f; }

  h16* tb = &tbuf[w][0];
  const int gw = blockIdx.x * 4 + w;
  for (int tile = gw; tile < NTILES; tile += gridDim.x * 4) {
    const int p = tile * 16 + ln;
    const bool act = p < PP;

    // A fragments: load z row chunk, BN+sine, repack to f16
    f16x8 afr[4];
#pragma unroll
    for (int ks = 0; ks < 4; ++ks) {
      f16x8 a;
      if (act) {
        const f16x8 raw = *(const f16x8*)(z + (size_t)p * 128 + ks * 32 + q * 8);
#pragma unroll
        for (int j = 0; j < 8; ++j) {
          const int c = ks * 32 + q * 8 + j;
          const float h = fmaf((float)raw[j], sc_s[c], sh_s[c]);
          a[j] = (h16)__sinf(h);
        }
      } else {
#pragma unroll
        for (int j = 0; j < 8; ++j) a[j] = (h16)0.f;
      }
      afr[ks] = a;
    }

    // GEMM: D[p][o] = sum_c act[p][c] * W[o][c]
    f32x4 acc[8];
#pragma unroll
    for (int nt = 0; nt < 8; ++nt) acc[nt] = (f32x4){0.f, 0.f, 0.f, 0.f};
#pragma unroll
    for (int ks = 0; ks < 4; ++ks)
#pragma unroll
      for (int nt = 0; nt < 8; ++nt)
        acc[nt] = __builtin_amdgcn_mfma_f32_16x16x32_f16(afr[ks], bfr[nt][ks],
                                                         acc[nt], 0, 0, 0);

    // stats + write D to per-wave LDS tile (row = point, col = channel)
#pragma unroll
    for (int nt = 0; nt < 8; ++nt) {
      const float d0 = acc[nt][0], d1 = acc[nt][1], d2 = acc[nt][2], d3 = acc[nt][3];
      sp[nt] += (d0 + d1) + (d2 + d3);
      qp[nt] += (d0 * d0 + d1 * d1) + (d2 * d2 + d3 * d3);
      const int c = nt * 16 + ln;
      tb[(q * 4 + 0) * 136 + c] = (h16)d0;
      tb[(q * 4 + 1) * 136 + c] = (h16)d1;
      tb[(q * 4 + 2) * 136 + c] = (h16)d2;
      tb[(q * 4 + 3) * 136 + c] = (h16)d3;
    }

    // read back rows, store coalesced (wave-private tile: no __syncthreads)
#pragma unroll
    for (int it = 0; it < 4; ++it) {
      const int m = it * 4 + q;     // row in tile
      const int ch = ln;            // 16B chunk in row
      const f16x8 v = *(const f16x8*)(tb + m * 136 + ch * 8);
      const int pp = tile * 16 + m;
      if (pp < PP) *(f16x8*)(z + (size_t)pp * 128 + ch * 8) = v;
    }
  }

  // final stats reduction: sum over quads (rows), then block, then atomics
#pragma unroll
  for (int nt = 0; nt < 8; ++nt) {
    sp[nt] += __shfl_xor(sp[nt], 16, 64);
    sp[nt] += __shfl_xor(sp[nt], 32, 64);
    qp[nt] += __shfl_xor(qp[nt], 16, 64);
    qp[nt] += __shfl_xor(qp[nt], 32, 64);
  }
  if (q == 0) {
#pragma unroll
    for (int nt = 0; nt < 8; ++nt) {
      red[w][nt * 16 + ln] = (double)sp[nt];
      red[w][128 + nt * 16 + ln] = (double)qp[nt];
    }
  }
  __syncthreads();
  double v = red[0][t] + red[1][t] + red[2][t] + red[3][t];
  atomicAdd(&gso[t], v);
}

// ---------------------------------------------------------------------------
// Final conv (128->1) with BN7+sine, z point-major. Wave per 16-point tile,
// A-fragment-pattern loads, partial dot per lane, quad butterfly, store 16.
// ---------------------------------------------------------------------------
__global__ __launch_bounds__(256) void k_logits(
    const h16* __restrict__ z,
    const double* __restrict__ gsp,
    const float* __restrict__ gamma,
    const float* __restrict__ beta,
    const float* __restrict__ fw,
    const float* __restrict__ fb,
    float* __restrict__ logits)
{
  __shared__ float sc_s[128], sh_s[128], fws[128];
  const int t = threadIdx.x;
  if (t < 128) {
    const double n = (double)PP;
    const double mu = gsp[t] / n;
    const double var = gsp[128 + t] / n - mu * mu;
    const float rstd = (float)(1.0 / sqrt(var + 1e-5));
    const float sc = rstd * gamma[t];
    sc_s[t] = sc;
    sh_s[t] = beta[t] - (float)mu * sc;
    fws[t] = fw[t];
  }
  __syncthreads();

  const int w = t >> 6;
  const int lane = t & 63;
  const int ln = lane & 15;
  const int q = lane >> 4;
  const float fbv = fb[0];

  const int gw = blockIdx.x * 4 + w;
  for (int tile = gw; tile < NTILES; tile += gridDim.x * 4) {
    const int p = tile * 16 + ln;
    float part = 0.f;
    if (p < PP) {
#pragma unroll
      for (int ks = 0; ks < 4; ++ks) {
        const f16x8 raw = *(const f16x8*)(z + (size_t)p * 128 + ks * 32 + q * 8);
#pragma unroll
        for (int j = 0; j < 8; ++j) {
          const int c = ks * 32 + q * 8 + j;
          part = fmaf(fws[c], __sinf(fmaf((float)raw[j], sc_s[c], sh_s[c])), part);
        }
      }
    }
    part += __shfl_xor(part, 16, 64);
    part += __shfl_xor(part, 32, 64);
    if (q == 0 && p < PP) logits[p] = part + fbv;
  }
}

// ---------------------------------------------------------------------------
// Softmax over K=20 per m + gather-weighted sum of x_feat rows. 1 wave per m.
// ---------------------------------------------------------------------------
__global__ __launch_bounds__(256) void k_out(
    const float* __restrict__ logits,  // [PP]
    const int* __restrict__ idx,       // [MM][KK]
    const float* __restrict__ xf,      // [NF][128]
    float* __restrict__ out)           // [MM][128]
{
  const int gw = (int)((blockIdx.x * 256 + threadIdx.x) >> 6);
  const int lane = threadIdx.x & 63;
  if (gw >= MM) return;
  const int m = gw;

  float l[KK];
#pragma unroll
  for (int k = 0; k < KK; ++k) l[k] = logits[m * KK + k];
  float mx = l[0];
#pragma unroll
  for (int k = 1; k < KK; ++k) mx = fmaxf(mx, l[k]);
  float ssum = 0.f;
#pragma unroll
  for (int k = 0; k < KK; ++k) { l[k] = __expf(l[k] - mx); ssum += l[k]; }
  const float inv = 1.f / ssum;

  float a0 = 0.f, a1 = 0.f;
#pragma unroll
  for (int k = 0; k < KK; ++k) {
    const int r = idx[m * KK + k];
    const float wk = l[k] * inv;
    a0 = fmaf(wk, xf[r * 128 + lane], a0);
    a1 = fmaf(wk, xf[r * 128 + 64 + lane], a1);
  }
  out[m * 128 + lane] = a0;
  out[m * 128 + 64 + lane] = a1;
}

// ---------------------------------------------------------------------------
// Fallback (small workspace): recompute chain in registers per point.
// ---------------------------------------------------------------------------
__global__ __launch_bounds__(256) void k_chain(
    const float* __restrict__ up,
    const float* __restrict__ w0,
    const float* __restrict__ wc,
    const float* __restrict__ gam,
    const float* __restrict__ bet,
    const double* __restrict__ gs,
    double* __restrict__ gso,
    int jl, int mode,
    const float* __restrict__ fw,
    const float* __restrict__ fb,
    float* __restrict__ logits)
{
  __shared__ float sc_s[8][128], sh_s[8][128];
  __shared__ double bred[4][256];
  const int t = threadIdx.x;
  const int lane = t & 63;

  const int nbn = (mode == 0) ? jl : 8;
  for (int i = t; i < nbn * 128; i += 256) {
    const int L = i >> 7, c = i & 127;
    const double n = (double)PP;
    const double mu = gs[L * 256 + c] / n;
    const double var = gs[L * 256 + 128 + c] / n - mu * mu;
    const float rstd = (float)(1.0 / sqrt(var + 1e-5));
    const float sc = rstd * gam[L * 128 + c];
    sc_s[L][c] = sc;
    sh_s[L][c] = bet[L * 128 + c] - (float)mu * sc;
  }
  __syncthreads();

  double lS0 = 0, lS1 = 0, lQ0 = 0, lQ1 = 0;

  for (int p0 = blockIdx.x * 256; p0 < PP; p0 += gridDim.x * 256) {
    const int p = p0 + t;
    const bool act = p < PP;

    float a[128];
    {
      float u[7];
#pragma unroll
      for (int c = 0; c < 7; ++c) u[c] = act ? up[c * PP + p] : 0.f;
#pragma unroll 1
      for (int och = 0; och < 16; ++och) {
#pragma unroll
        for (int j = 0; j < 8; ++j) {
          float acc = 0.f;
#pragma unroll
          for (int c = 0; c < 7; ++c)
            acc = fmaf(w0[(och * 8 + j) * 7 + c], u[c], acc);
          a[och * 8 + j] = acc;
        }
      }
    }

#pragma unroll 1
    for (int L = 0; L < jl; ++L) {
#pragma unroll
      for (int c = 0; c < 128; ++c)
        a[c] = act ? __sinf(fmaf(a[c], sc_s[L][c], sh_s[L][c])) : 0.f;
      float b[128];
      const float* W = wc + (size_t)L * 128 * 128;
#pragma unroll 1
      for (int och = 0; och < 16; ++och) {
#pragma unroll
        for (int j = 0; j < 8; ++j) {
          float acc = 0.f;
#pragma unroll
          for (int c = 0; c < 128; ++c)
            acc = fmaf(W[(och * 8 + j) * 128 + c], a[c], acc);
          b[och * 8 + j] = acc;
        }
      }
#pragma unroll
      for (int c = 0; c < 128; ++c) a[c] = b[c];
    }

    if (mode == 0) {
#pragma unroll
      for (int o = 0; o < 128; ++o) {
        float s = a[o];
        float qv = a[o] * a[o];
#pragma unroll
        for (int d = 32; d > 0; d >>= 1) {
          s += __shfl_xor(s, d, 64);
          qv += __shfl_xor(qv, d, 64);
        }
        if ((o & 63) == lane) {
          if (o < 64) { lS0 += (double)s; lQ0 += (double)qv; }
          else        { lS1 += (double)s; lQ1 += (double)qv; }
        }
      }
    } else if (act) {
      float acc = fb[0];
#pragma unroll
      for (int c = 0; c < 128; ++c) {
        const float h = fmaf(a[c], sc_s[7][c], sh_s[7][c]);
        acc = fmaf(fw[c], __sinf(h), acc);
      }
      logits[p] = acc;
    }
  }

  if (mode == 0) {
    const int w = t >> 6;
    bred[w][lane]       = lS0;
    bred[w][64 + lane]  = lS1;
    bred[w][128 + lane] = lQ0;
    bred[w][192 + lane] = lQ1;
    __syncthreads();
    double v = bred[0][t] + bred[1][t] + bred[2][t] + bred[3][t];
    atomicAdd(&gso[t], v);
  }
}

// ---------------------------------------------------------------------------
extern "C" void kernel_launch(void* const* d_in, const int* in_sizes, int n_in,
                              void* d_out, int out_size, void* d_ws, size_t ws_size,
                              hipStream_t stream) {
  const float* xf  = (const float*)d_in[0];  // (1, N, 128)
  const float* up  = (const float*)d_in[1];  // (1, 7, M, K)  == [7][PP]
  const int*   idx = (const int*)d_in[2];    // (1, M, K)
  const float* w0  = (const float*)d_in[3];  // (128, 7)
  const float* wc  = (const float*)d_in[4];  // (7, 128, 128)
  const float* gam = (const float*)d_in[5];  // (8, 128)
  const float* bet = (const float*)d_in[6];  // (8, 128)
  const float* fw  = (const float*)d_in[7];  // (1, 128)
  const float* fb  = (const float*)d_in[8];  // (1,)
  float* out = (float*)d_out;

  char* ws = (char*)d_ws;
  const size_t zb     = (size_t)PP * 128 * sizeof(h16);   // 182,461,440 B
  const size_t statsb = 8 * 256 * sizeof(double);         // 16,384 B
  const size_t logb   = (size_t)PP * sizeof(float);       // 2,850,960 B
  const int NB = 1024;
  const int nbo = (MM + 3) / 4;

  if (ws_size >= zb + statsb + logb) {
    // Fast path: point-major fp16 z + MFMA layers (needs ~176.7 MiB).
    h16* z = (h16*)ws;
    double* gs = (double*)(ws + zb);
    float* logits = (float*)(ws + zb + statsb);

    k_zero<<<1, 256, 0, stream>>>(gs);
    k_layer0<<<NB, 256, 0, stream>>>(up, w0, z, gs);
    for (int i = 1; i <= 7; ++i) {
      k_layer<<<NB, 256, 0, stream>>>(z,
                                      gs + (size_t)(i - 1) * 256,
                                      gs + (size_t)i * 256,
                                      wc + (size_t)(i - 1) * 128 * 128,
                                      gam + (size_t)(i - 1) * 128,
                                      bet + (size_t)(i - 1) * 128);
    }
    k_logits<<<NB, 256, 0, stream>>>(z, gs + 7 * 256, gam + 7 * 128,
                                     bet + 7 * 128, fw, fb, logits);
    k_out<<<nbo, 256, 0, stream>>>(logits, idx, xf, out);
  } else {
    // Fallback: recompute chain, needs only ~2.9 MiB of workspace.
    double* gs = (double*)ws;
    float* logits = (float*)(ws + statsb);

    k_zero<<<1, 256, 0, stream>>>(gs);
    for (int j = 0; j <= 7; ++j) {
      k_chain<<<NB, 256, 0, stream>>>(up, w0, wc, gam, bet, gs,
                                      gs + (size_t)j * 256, j, 0,
                                      fw, fb, logits);
    }
    k_chain<<<NB, 256, 0, stream>>>(up, w0, wc, gam, bet, gs,
                                    nullptr, 7, 1, fw, fb, logits);
    k_out<<<nbo, 256, 0, stream>>>(logits, idx, xf, out);
  }
}